// Round 8
// baseline (92.623 us; speedup 1.0000x reference)
//
#include <hip/hip_runtime.h>
#include <hip/hip_bf16.h>

#define T_TOK 256
#define C_DIM 1024
#define H_DIM 2048
#define E_NUM 8

typedef __attribute__((ext_vector_type(4))) float f32x4;
typedef __attribute__((ext_vector_type(8))) short short8;

// workspace layout (bytes)
#define WS_CNT    0
#define WS_LIST   1024
#define WS_XBF    16384                      // 256*1024*2 = 512 KB
#define WS_HBUF   (1u<<20)                   // 1 MB bf16 (expert h)
#define WS_HSBUF  (2u<<20)                   // 1 MB bf16 (shared h)
#define WS_YS     (3u<<20)                   // 1 MB f32 (shared y)

__device__ __forceinline__ ushort f2bf(float f) {
    __hip_bfloat16 h = __float2bfloat16(f);
    return *reinterpret_cast<ushort*>(&h);
}

__device__ __forceinline__ short8 pack8(float4 a, float4 b) {
    short8 s;
    s[0] = (short)f2bf(a.x); s[1] = (short)f2bf(a.y);
    s[2] = (short)f2bf(a.z); s[3] = (short)f2bf(a.w);
    s[4] = (short)f2bf(b.x); s[5] = (short)f2bf(b.y);
    s[6] = (short)f2bf(b.z); s[7] = (short)f2bf(b.w);
    return s;
}

// async global->LDS DMA, 16B per lane. lds dest is wave-uniform base + lane*16;
// global src is per-lane (pre-swizzled for conflict-free reads).
__device__ __forceinline__ void gload16(const void* g, void* l) {
    __builtin_amdgcn_global_load_lds((const __attribute__((address_space(1))) void*)g,
                                     (__attribute__((address_space(3))) void*)l, 16, 0, 0);
}

#define MFMA(a, b, c) __builtin_amdgcn_mfma_f32_16x16x32_bf16((a), (b), (c), 0, 0, 0)

// counted vmem wait + scheduling fence (rule #18)
#define VMWAIT(N) do { asm volatile("s_waitcnt vmcnt(" #N ")" ::: "memory"); \
                       __builtin_amdgcn_sched_barrier(0); } while (0)
#define BARRIER() do { __builtin_amdgcn_s_barrier(); \
                       __builtin_amdgcn_sched_barrier(0); } while (0)

// router + x->bf16 prep fused. 1 block per token.
__global__ __launch_bounds__(256) void router_kernel(
    const float* __restrict__ x, const float* __restrict__ router,
    int* __restrict__ cnt, int* __restrict__ list, ushort* __restrict__ xbf)
{
    const int t = blockIdx.x;
    const int tid = threadIdx.x;
    float4 xv = reinterpret_cast<const float4*>(x + (size_t)t * C_DIM)[tid];
    ushort4 xb;
    xb.x = f2bf(xv.x); xb.y = f2bf(xv.y); xb.z = f2bf(xv.z); xb.w = f2bf(xv.w);
    *reinterpret_cast<ushort4*>(xbf + (size_t)t * C_DIM + tid * 4) = xb;

    float p[E_NUM];
#pragma unroll
    for (int e = 0; e < E_NUM; e++) {
        float4 rv = reinterpret_cast<const float4*>(router + (size_t)e * C_DIM)[tid];
        p[e] = xv.x * rv.x + xv.y * rv.y + xv.z * rv.z + xv.w * rv.w;
    }
#pragma unroll
    for (int e = 0; e < E_NUM; e++) {
#pragma unroll
        for (int off = 32; off >= 1; off >>= 1)
            p[e] += __shfl_down(p[e], off, 64);
    }
    __shared__ float red[E_NUM][4];
    const int lane = tid & 63, wv = tid >> 6;
    if (lane == 0) {
#pragma unroll
        for (int e = 0; e < E_NUM; e++) red[e][wv] = p[e];
    }
    __syncthreads();
    if (tid == 0) {
        float best = -3.4e38f; int bi = 0;
#pragma unroll
        for (int e = 0; e < E_NUM; e++) {
            float v = red[e][0] + red[e][1] + red[e][2] + red[e][3];
            if (v > best) { best = v; bi = e; }
        }
        int pos = atomicAdd(&cnt[bi], 1);
        list[bi * T_TOK + pos] = t;
    }
}

// ug: BM=32 tokens x BN=32 h-rows, K=1024 in 16 chunks of 64 f32.
// Triple-buffered LDS, depth-3 global_load_lds prefetch, counted vmcnt,
// raw s_barrier (no vmcnt(0) drain). grid (9 [8=shared], H/32=64, 8 tiles).
__global__ __launch_bounds__(256, 2) void ug_mfma(
    const ushort* __restrict__ xbf, const float* __restrict__ up, const float* __restrict__ gate,
    const float* __restrict__ w_up_s, const float* __restrict__ w_gate_s,
    const int* __restrict__ cnt, const int* __restrict__ list,
    ushort* __restrict__ hbuf, ushort* __restrict__ hsbuf)
{
    const int e = blockIdx.x, by = blockIdx.y, tt = blockIdx.z;
    const bool sh = (e == E_NUM);
    const int n = sh ? T_TOK : cnt[e];
    if (tt * 32 >= n) return;
    const int tid = threadIdx.x, lane = tid & 63, wv = tid >> 6;

    __shared__ float4 WuS[3][512];   // [32 rows][16 units] per buf, swizzled
    __shared__ float4 WgS[3][512];
    __shared__ ushort XS[3][2048];   // [32 rows][8 units of 8 bf16] per buf
    __shared__ int toks_s[32];
    if (tid < 32) {
        int t = tt * 32 + tid;
        toks_s[tid] = (t < n) ? (sh ? t : list[e * T_TOK + t]) : -1;
    }
    __syncthreads();

    const int n0 = by * 32;
    const float* __restrict__ ub = (sh ? w_up_s   : up   + (size_t)e * H_DIM * C_DIM) + (size_t)n0 * C_DIM;
    const float* __restrict__ gb = (sh ? w_gate_s : gate + (size_t)e * H_DIM * C_DIM) + (size_t)n0 * C_DIM;

    // per-wave staging: slots s = wv*5 + i, i<5. s<8: Wu, s<16: Wg, s<20: X.
#define UG_STAGE(tc, bf) do { \
        const int kc0_ = (tc) * 64; \
        _Pragma("unroll") \
        for (int i = 0; i < 5; i++) { \
            int s = wv * 5 + i; \
            if (s < 16) { \
                int p = (s & 7) * 64 + lane; \
                int row = p >> 4, ul = p & 15; \
                int col = ((ul ^ (row & 7)) << 2); \
                const float* src = (s < 8 ? ub : gb) + (size_t)row * C_DIM + kc0_ + col; \
                gload16(src, (void*)&(s < 8 ? WuS : WgS)[bf][(s & 7) * 64]); \
            } else { \
                int q = (s - 16) * 64 + lane; \
                int row = q >> 3, xl = q & 7; \
                int col = ((xl ^ (row & 7)) << 3); \
                int tok = toks_s[row]; if (tok < 0) tok = 0; \
                const ushort* src = xbf + (size_t)tok * C_DIM + kc0_ + col; \
                gload16(src, (void*)&XS[bf][(s - 16) * 512]); \
            } \
        } \
    } while (0)

    const int lc = lane & 15, kg = lane >> 4;
    const int mf = wv >> 1, nf = wv & 1;
    const int rm = mf * 16 + lc, sm = rm & 7;
    const int rn = nf * 16 + lc, sn = rn & 7;
    f32x4 au = {0,0,0,0}, ag = {0,0,0,0};

    UG_STAGE(0, 0);
    UG_STAGE(1, 1);
    UG_STAGE(2, 2);

#pragma unroll 1
    for (int t = 0; t < 16; t++) {
        const int b = t % 3;
        // wait for chunk t's 5 loads (oldest); keep t+1/t+2 (10) in flight
        if (t <= 13)      VMWAIT(10);
        else if (t == 14) VMWAIT(5);
        else              VMWAIT(0);
        BARRIER();                      // all waves: chunk t landed
#pragma unroll
        for (int k32 = 0; k32 < 2; k32++) {
            int xunit = rm * 8 + ((k32 * 4 + kg) ^ sm);
            short8 a = *reinterpret_cast<const short8*>(&XS[b][xunit * 8]);
            int ks = k32 * 8 + kg * 2;
            float4 w0 = WuS[b][rn * 16 + (ks ^ sn)];
            float4 w1 = WuS[b][rn * 16 + ((ks + 1) ^ sn)];
            au = MFMA(a, pack8(w0, w1), au);
            float4 g0 = WgS[b][rn * 16 + (ks ^ sn)];
            float4 g1 = WgS[b][rn * 16 + ((ks + 1) ^ sn)];
            ag = MFMA(a, pack8(g0, g1), ag);
        }
        BARRIER();                      // all waves done reading buf b
        if (t + 3 < 16) UG_STAGE(t + 3, b);
    }
#undef UG_STAGE

    ushort* __restrict__ outp = sh ? hsbuf : hbuf;
    const int hcol = n0 + nf * 16 + lc;
#pragma unroll
    for (int j = 0; j < 4; j++) {
        int m = mf * 16 + kg * 4 + j;
        int tok = toks_s[m];
        if (tok >= 0) {
            float g = ag[j], u = au[j];
            float hv = u * (g / (1.f + __expf(-g)));
            outp[(size_t)tok * H_DIM + hcol] = f2bf(hv);
        }
    }
}

// down: BM=32 tokens x BN=32 c-rows, K=2048 in 32 chunks of 64.
// grid (9 [8=shared], C/32=32, 8 token-tiles). Same pipeline, 3 loads/chunk.
__global__ __launch_bounds__(256, 2) void down_mfma(
    const float* __restrict__ dwn, const float* __restrict__ w_down_s,
    const ushort* __restrict__ hbuf, const ushort* __restrict__ hsbuf,
    const int* __restrict__ cnt, const int* __restrict__ list,
    float* __restrict__ y, float* __restrict__ yspart)
{
    const int e = blockIdx.x, by = blockIdx.y, tt = blockIdx.z;
    const bool sh = (e == E_NUM);
    const int n = sh ? T_TOK : cnt[e];
    if (tt * 32 >= n) return;
    const int tid = threadIdx.x, lane = tid & 63, wv = tid >> 6;

    __shared__ float4 WdS[3][512];
    __shared__ ushort HxS[3][2048];
    __shared__ int toks_s[32];
    if (tid < 32) {
        int t = tt * 32 + tid;
        toks_s[tid] = (t < n) ? (sh ? t : list[e * T_TOK + t]) : -1;
    }
    __syncthreads();

    const int n0 = by * 32;
    const float* __restrict__ db = (sh ? w_down_s : dwn + (size_t)e * C_DIM * H_DIM) + (size_t)n0 * H_DIM;
    const ushort* __restrict__ hin = sh ? hsbuf : hbuf;

    // slots s = wv*3 + i, i<3. s<8: Wd, s<12: Hx.
#define DN_STAGE(tc, bf) do { \
        const int kc0_ = (tc) * 64; \
        _Pragma("unroll") \
        for (int i = 0; i < 3; i++) { \
            int s = wv * 3 + i; \
            if (s < 8) { \
                int p = s * 64 + lane; \
                int row = p >> 4, ul = p & 15; \
                int col = ((ul ^ (row & 7)) << 2); \
                const float* src = db + (size_t)row * H_DIM + kc0_ + col; \
                gload16(src, (void*)&WdS[bf][s * 64]); \
            } else { \
                int q = (s - 8) * 64 + lane; \
                int row = q >> 3, xl = q & 7; \
                int col = ((xl ^ (row & 7)) << 3); \
                int tok = toks_s[row]; if (tok < 0) tok = 0; \
                const ushort* src = hin + (size_t)tok * H_DIM + kc0_ + col; \
                gload16(src, (void*)&HxS[bf][(s - 8) * 512]); \
            } \
        } \
    } while (0)

    const int lc = lane & 15, kg = lane >> 4;
    const int mf = wv >> 1, nf = wv & 1;
    const int rm = mf * 16 + lc, sm = rm & 7;
    const int rn = nf * 16 + lc, sn = rn & 7;
    f32x4 acc = {0,0,0,0};

    DN_STAGE(0, 0);
    DN_STAGE(1, 1);
    DN_STAGE(2, 2);

#pragma unroll 1
    for (int t = 0; t < 32; t++) {
        const int b = t % 3;
        if (t <= 29)      VMWAIT(6);
        else if (t == 30) VMWAIT(3);
        else              VMWAIT(0);
        BARRIER();
#pragma unroll
        for (int k32 = 0; k32 < 2; k32++) {
            int xunit = rm * 8 + ((k32 * 4 + kg) ^ sm);
            short8 a = *reinterpret_cast<const short8*>(&HxS[b][xunit * 8]);
            int ks = k32 * 8 + kg * 2;
            float4 w0 = WdS[b][rn * 16 + (ks ^ sn)];
            float4 w1 = WdS[b][rn * 16 + ((ks + 1) ^ sn)];
            acc = MFMA(a, pack8(w0, w1), acc);
        }
        BARRIER();
        if (t + 3 < 32) DN_STAGE(t + 3, b);
    }
#undef DN_STAGE

    float* __restrict__ outp = sh ? yspart : y;
    const int cglob = n0 + nf * 16 + lc;
#pragma unroll
    for (int j = 0; j < 4; j++) {
        int m = mf * 16 + kg * 4 + j;
        int tok = toks_s[m];
        if (tok >= 0) outp[(size_t)tok * C_DIM + cglob] = acc[j];
    }
}

__global__ __launch_bounds__(256) void add_kernel(float* __restrict__ y, const float* __restrict__ ys)
{
    int i = blockIdx.x * 256 + threadIdx.x;
    float4 a = reinterpret_cast<float4*>(y)[i];
    float4 b = reinterpret_cast<const float4*>(ys)[i];
    a.x += b.x; a.y += b.y; a.z += b.z; a.w += b.w;
    reinterpret_cast<float4*>(y)[i] = a;
}

extern "C" void kernel_launch(void* const* d_in, const int* in_sizes, int n_in,
                              void* d_out, int out_size, void* d_ws, size_t ws_size,
                              hipStream_t stream)
{
    const float* x        = (const float*)d_in[0];
    const float* up       = (const float*)d_in[1];
    const float* gate     = (const float*)d_in[2];
    const float* dwn      = (const float*)d_in[3];
    const float* router   = (const float*)d_in[4];
    const float* w_up_s   = (const float*)d_in[5];
    const float* w_gate_s = (const float*)d_in[6];
    const float* w_down_s = (const float*)d_in[7];

    char* ws = (char*)d_ws;
    int* cnt      = (int*)(ws + WS_CNT);
    int* list     = (int*)(ws + WS_LIST);
    ushort* xbf   = (ushort*)(ws + WS_XBF);
    ushort* hbuf  = (ushort*)(ws + WS_HBUF);
    ushort* hsbuf = (ushort*)(ws + WS_HSBUF);
    float* yspart = (float*)(ws + WS_YS);
    float* y = (float*)d_out;

    hipMemsetAsync(cnt, 0, E_NUM * sizeof(int), stream);
    router_kernel<<<T_TOK, 256, 0, stream>>>(x, router, cnt, list, xbf);
    ug_mfma<<<dim3(E_NUM + 1, H_DIM / 32, 8), 256, 0, stream>>>(
        xbf, up, gate, w_up_s, w_gate_s, cnt, list, hbuf, hsbuf);
    down_mfma<<<dim3(E_NUM + 1, C_DIM / 32, 8), 256, 0, stream>>>(
        dwn, w_down_s, hbuf, hsbuf, cnt, list, y, yspart);
    add_kernel<<<(T_TOK * C_DIM / 4) / 256, 256, 0, stream>>>(y, yspart);
}